// Round 1
// baseline (1276.339 us; speedup 1.0000x reference)
//
#include <hip/hip_runtime.h>
#include <hip/hip_bf16.h>
#include <math.h>

#define F_IN 128
#define H1c 16
#define H2c 32
#define H3c 64
#define H4c 32
#define NCc 16

typedef unsigned int u32;

// ---------------- utility kernels ----------------

__global__ __launch_bounds__(256) void k_zero_u32(u32* __restrict__ p, int n) {
    int i = blockIdx.x * blockDim.x + threadIdx.x;
    if (i < n) p[i] = 0u;
}

// Detect whether edge_index is int32 (stride 1) or int64 (stride 2, little-endian
// low word holds the value since 0 <= idx < N < 2^31). If the odd 32-bit words of
// the first 8192 words are ALL zero, it's int64.
__global__ __launch_bounds__(256) void k_detect(const u32* __restrict__ ei, u32* __restrict__ flags) {
    __shared__ int nz;
    if (threadIdx.x == 0) nz = 0;
    __syncthreads();
    for (int i = threadIdx.x; 2 * i + 1 < 8192; i += blockDim.x) {
        if (ei[2 * i + 1] != 0u) atomicAdd(&nz, 1);
    }
    __syncthreads();
    if (threadIdx.x == 0) flags[0] = (nz == 0) ? 2u : 1u;
}

__global__ __launch_bounds__(256) void k_count(const u32* __restrict__ ei, int E,
                                               const u32* __restrict__ flags,
                                               u32* __restrict__ cnt) {
    int e = blockIdx.x * blockDim.x + threadIdx.x;
    u32 strd = flags[0];
    if (e < E) {
        u32 d = ei[((size_t)E + (size_t)e) * strd];
        atomicAdd(&cnt[d], 1u);
    }
}

// chunk-local exclusive scan over 512-element chunks (Hillis-Steele)
__global__ __launch_bounds__(512) void k_scan1(const u32* __restrict__ cnt, int n,
                                               u32* __restrict__ off, u32* __restrict__ bsum) {
    __shared__ u32 s[512];
    int i = blockIdx.x * 512 + threadIdx.x;
    u32 v = (i < n) ? cnt[i] : 0u;
    s[threadIdx.x] = v;
    __syncthreads();
    for (int o = 1; o < 512; o <<= 1) {
        u32 t = (threadIdx.x >= (u32)o) ? s[threadIdx.x - o] : 0u;
        __syncthreads();
        s[threadIdx.x] += t;
        __syncthreads();
    }
    if (i < n) off[i] = s[threadIdx.x] - v;   // exclusive within chunk
    if (threadIdx.x == 511) bsum[blockIdx.x] = s[511];
}

// exclusive scan of up to 256 block sums, in place
__global__ __launch_bounds__(256) void k_scan2(u32* __restrict__ bsum, int nb) {
    __shared__ u32 s[256];
    u32 v = (threadIdx.x < (u32)nb) ? bsum[threadIdx.x] : 0u;
    s[threadIdx.x] = v;
    __syncthreads();
    for (int o = 1; o < 256; o <<= 1) {
        u32 t = (threadIdx.x >= (u32)o) ? s[threadIdx.x - o] : 0u;
        __syncthreads();
        s[threadIdx.x] += t;
        __syncthreads();
    }
    if (threadIdx.x < (u32)nb) bsum[threadIdx.x] = s[threadIdx.x] - v;
}

__global__ __launch_bounds__(256) void k_finalize(const u32* __restrict__ cnt, u32* __restrict__ off,
                                                  const u32* __restrict__ bsum, u32* __restrict__ cursor,
                                                  float* __restrict__ dinv, int n) {
    int i = blockIdx.x * blockDim.x + threadIdx.x;
    if (i < n) {
        u32 o = off[i] + bsum[i >> 9];
        off[i] = o;
        cursor[i] = o;
        dinv[i] = 1.0f / sqrtf((float)(cnt[i] + 1u));  // +1 self-loop; deg>=1 always
    }
}

__global__ __launch_bounds__(256) void k_fill(const u32* __restrict__ ei, int E,
                                              const u32* __restrict__ flags,
                                              u32* __restrict__ cursor, u32* __restrict__ perm) {
    int e = blockIdx.x * blockDim.x + threadIdx.x;
    u32 strd = flags[0];
    if (e < E) {
        u32 s = ei[(size_t)e * strd];
        u32 d = ei[((size_t)E + (size_t)e) * strd];
        u32 p = atomicAdd(&cursor[d], 1u);
        perm[p] = s;
    }
}

// h1s[r,:] = (x[r,:] @ W1) * dinv[r]   (pre-scaled by dinv for gather-side factoring)
__global__ __launch_bounds__(256) void k_xw1(const float* __restrict__ x, const float* __restrict__ W1,
                                             const float* __restrict__ dinv, float* __restrict__ h1s, int n) {
    __shared__ float Ws[F_IN * H1c];  // 8 KB
    for (int t = threadIdx.x; t < F_IN * H1c; t += 256) Ws[t] = W1[t];
    __syncthreads();
    int r = blockIdx.x * 16 + (threadIdx.x >> 4);
    int c = threadIdx.x & 15;
    if (r >= n) return;
    const float* xr = x + (size_t)r * F_IN;
    float a0 = 0.f, a1 = 0.f;
    #pragma unroll
    for (int k = 0; k < F_IN; k += 4) {
        float4 xv = *reinterpret_cast<const float4*>(xr + k);
        a0 += xv.x * Ws[(k + 0) * H1c + c];
        a1 += xv.y * Ws[(k + 1) * H1c + c];
        a0 += xv.z * Ws[(k + 2) * H1c + c];
        a1 += xv.w * Ws[(k + 3) * H1c + c];
    }
    h1s[(size_t)r * H1c + c] = (a0 + a1) * dinv[r];
}

// Gather-aggregate layer 1 (16 lanes/node), finish GCN1 (+bias, ReLU), then @W2,
// pre-scale by dinv -> h2s
__global__ __launch_bounds__(256) void k_agg1_w2(const float* __restrict__ h1s, const u32* __restrict__ perm,
                                                 const u32* __restrict__ off, const u32* __restrict__ cnt,
                                                 const float* __restrict__ dinv, const float* __restrict__ b1,
                                                 const float* __restrict__ W2, float* __restrict__ h2s, int n) {
    __shared__ float W2s[H1c * H2c];      // 512 floats
    __shared__ float h1L[16][H1c + 1];
    for (int t = threadIdx.x; t < H1c * H2c; t += 256) W2s[t] = W2[t];

    int g = threadIdx.x >> 4, j = threadIdx.x & 15;
    int r = blockIdx.x * 16 + g;
    float hv = 0.f;
    if (r < n) {
        u32 s0 = off[r], len = cnt[r];
        float a0 = 0.f, a1 = 0.f, a2 = 0.f, a3 = 0.f;
        u32 it = 0;
        for (; it + 4 <= len; it += 4) {
            u32 e0 = perm[s0 + it], e1 = perm[s0 + it + 1];
            u32 e2 = perm[s0 + it + 2], e3 = perm[s0 + it + 3];
            a0 += h1s[(size_t)e0 * H1c + j];
            a1 += h1s[(size_t)e1 * H1c + j];
            a2 += h1s[(size_t)e2 * H1c + j];
            a3 += h1s[(size_t)e3 * H1c + j];
        }
        for (; it < len; ++it) a0 += h1s[(size_t)perm[s0 + it] * H1c + j];
        float acc = (a0 + a1) + (a2 + a3);
        float dv = dinv[r];
        hv = fmaxf(dv * (acc + h1s[(size_t)r * H1c + j]) + b1[j], 0.f);
    }
    h1L[g][j] = hv;
    __syncthreads();

    int c = threadIdx.x & 31, g2 = threadIdx.x >> 5;
    #pragma unroll
    for (int p = 0; p < 2; ++p) {
        int rr = g2 + p * 8;
        int n2 = blockIdx.x * 16 + rr;
        if (n2 < n) {
            float acc2 = 0.f;
            #pragma unroll
            for (int jj = 0; jj < H1c; ++jj) acc2 += h1L[rr][jj] * W2s[jj * H2c + c];
            h2s[(size_t)n2 * H2c + c] = acc2 * dinv[n2];
        }
    }
}

// Gather-aggregate layer 2 (32 lanes/node), finish GCN2 (+bias, ReLU) -> h2post
__global__ __launch_bounds__(256) void k_agg2(const float* __restrict__ h2s, const u32* __restrict__ perm,
                                              const u32* __restrict__ off, const u32* __restrict__ cnt,
                                              const float* __restrict__ dinv, const float* __restrict__ b2,
                                              float* __restrict__ h2post, int n) {
    int g = threadIdx.x >> 5, j = threadIdx.x & 31;
    int r = blockIdx.x * 8 + g;
    if (r >= n) return;
    u32 s0 = off[r], len = cnt[r];
    float a0 = 0.f, a1 = 0.f, a2 = 0.f, a3 = 0.f;
    u32 it = 0;
    for (; it + 4 <= len; it += 4) {
        u32 e0 = perm[s0 + it], e1 = perm[s0 + it + 1];
        u32 e2 = perm[s0 + it + 2], e3 = perm[s0 + it + 3];
        a0 += h2s[(size_t)e0 * H2c + j];
        a1 += h2s[(size_t)e1 * H2c + j];
        a2 += h2s[(size_t)e2 * H2c + j];
        a3 += h2s[(size_t)e3 * H2c + j];
    }
    for (; it < len; ++it) a0 += h2s[(size_t)perm[s0 + it] * H2c + j];
    float acc = (a0 + a1) + (a2 + a3);
    float dv = dinv[r];
    h2post[(size_t)r * H2c + j] = fmaxf(dv * (acc + h2s[(size_t)r * H2c + j]) + b2[j], 0.f);
}

// Fused MLP: one thread per node. Weights staged in LDS (broadcast reads).
__global__ __launch_bounds__(256) void k_mlp(const float* __restrict__ h2post,
                                             const float* __restrict__ Wf1, const float* __restrict__ bf1,
                                             const float* __restrict__ Wf2, const float* __restrict__ bf2,
                                             const float* __restrict__ Wf3, const float* __restrict__ bf3,
                                             float* __restrict__ out, int n) {
    __shared__ float W1s[H2c * H3c];  // 2048
    __shared__ float W2s[H3c * H4c];  // 2048
    __shared__ float W3s[H4c * NCc];  // 512
    __shared__ float b1s[H3c], b2s[H4c], b3s[NCc];
    for (int t = threadIdx.x; t < H2c * H3c; t += 256) W1s[t] = Wf1[t];
    for (int t = threadIdx.x; t < H3c * H4c; t += 256) W2s[t] = Wf2[t];
    for (int t = threadIdx.x; t < H4c * NCc; t += 256) W3s[t] = Wf3[t];
    if (threadIdx.x < H3c) b1s[threadIdx.x] = bf1[threadIdx.x];
    if (threadIdx.x < H4c) b2s[threadIdx.x] = bf2[threadIdx.x];
    if (threadIdx.x < NCc) b3s[threadIdx.x] = bf3[threadIdx.x];
    __syncthreads();

    int r = blockIdx.x * 256 + threadIdx.x;
    if (r >= n) return;

    float h2v[H2c];
    #pragma unroll
    for (int k = 0; k < H2c; k += 4) {
        float4 v = *reinterpret_cast<const float4*>(h2post + (size_t)r * H2c + k);
        h2v[k] = v.x; h2v[k + 1] = v.y; h2v[k + 2] = v.z; h2v[k + 3] = v.w;
    }
    float a4[H4c];
    #pragma unroll
    for (int k2 = 0; k2 < H4c; ++k2) a4[k2] = b2s[k2];
    #pragma unroll 4
    for (int j = 0; j < H3c; ++j) {
        float t = b1s[j];
        #pragma unroll
        for (int k = 0; k < H2c; ++k) t += h2v[k] * W1s[k * H3c + j];
        t = fmaxf(t, 0.f);
        #pragma unroll
        for (int k2 = 0; k2 < H4c; ++k2) a4[k2] += t * W2s[j * H4c + k2];
    }
    #pragma unroll
    for (int k2 = 0; k2 < H4c; ++k2) a4[k2] = fmaxf(a4[k2], 0.f);

    #pragma unroll
    for (int c0 = 0; c0 < NCc; c0 += 4) {
        float o0 = b3s[c0], o1 = b3s[c0 + 1], o2 = b3s[c0 + 2], o3 = b3s[c0 + 3];
        #pragma unroll
        for (int k2 = 0; k2 < H4c; ++k2) {
            float a = a4[k2];
            o0 += a * W3s[k2 * NCc + c0];
            o1 += a * W3s[k2 * NCc + c0 + 1];
            o2 += a * W3s[k2 * NCc + c0 + 2];
            o3 += a * W3s[k2 * NCc + c0 + 3];
        }
        *reinterpret_cast<float4*>(out + (size_t)r * NCc + c0) = make_float4(o0, o1, o2, o3);
    }
}

extern "C" void kernel_launch(void* const* d_in, const int* in_sizes, int n_in,
                              void* d_out, int out_size, void* d_ws, size_t ws_size,
                              hipStream_t stream) {
    const float* x   = (const float*)d_in[0];
    const float* W1  = (const float*)d_in[1];
    const float* b1  = (const float*)d_in[2];
    const float* W2  = (const float*)d_in[3];
    const float* b2  = (const float*)d_in[4];
    const float* Wf1 = (const float*)d_in[5];
    const float* bf1 = (const float*)d_in[6];
    const float* Wf2 = (const float*)d_in[7];
    const float* bf2 = (const float*)d_in[8];
    const float* Wf3 = (const float*)d_in[9];
    const float* bf3 = (const float*)d_in[10];
    const u32*   ei  = (const u32*)d_in[11];

    int N = in_sizes[0] / F_IN;
    int E = in_sizes[11] / 2;

    // workspace layout (bytes)
    char* w = (char*)d_ws;
    u32* cnt    = (u32*)w;   w += (size_t)N * 4;
    u32* off    = (u32*)w;   w += (size_t)N * 4;
    u32* cursor = (u32*)w;   w += (size_t)N * 4;
    u32* bsum   = (u32*)w;   w += 256 * 4;
    u32* flags  = (u32*)w;   w += 16 * 4;
    float* dinv = (float*)w; w += (size_t)N * 4;
    float* h1s  = (float*)w; w += (size_t)N * H1c * 4;
    float* h2s  = (float*)w; w += (size_t)N * H2c * 4;
    float* h2p  = (float*)w; w += (size_t)N * H2c * 4;
    u32* perm   = (u32*)w;   w += (size_t)E * 4;

    int nbN = (N + 255) / 256;
    int nbE = (E + 255) / 256;
    int nchunk = (N + 511) / 512;  // 196 <= 256, fits k_scan2

    k_detect<<<1, 256, 0, stream>>>(ei, flags);
    k_zero_u32<<<nbN, 256, 0, stream>>>(cnt, N);
    k_count<<<nbE, 256, 0, stream>>>(ei, E, flags, cnt);
    k_scan1<<<nchunk, 512, 0, stream>>>(cnt, N, off, bsum);
    k_scan2<<<1, 256, 0, stream>>>(bsum, nchunk);
    k_finalize<<<nbN, 256, 0, stream>>>(cnt, off, bsum, cursor, dinv, N);
    k_fill<<<nbE, 256, 0, stream>>>(ei, E, flags, cursor, perm);

    int nb16 = (N + 15) / 16;
    k_xw1<<<nb16, 256, 0, stream>>>(x, W1, dinv, h1s, N);
    k_agg1_w2<<<nb16, 256, 0, stream>>>(h1s, perm, off, cnt, dinv, b1, W2, h2s, N);
    int nb8 = (N + 7) / 8;
    k_agg2<<<nb8, 256, 0, stream>>>(h2s, perm, off, cnt, dinv, b2, h2p, N);
    k_mlp<<<nbN, 256, 0, stream>>>(h2p, Wf1, bf1, Wf2, bf2, Wf3, bf3, (float*)d_out, N);
}

// Round 2
// 709.288 us; speedup vs baseline: 1.7995x; 1.7995x over previous
//
#include <hip/hip_runtime.h>
#include <hip/hip_bf16.h>
#include <math.h>

#define F_IN 128
#define H1c 16
#define H2c 32
#define H3c 64
#define H4c 32
#define NCc 16

#define BMAX 4096        // max buckets (N <= 131072)
#define GPART 128        // partition groups (blocks in hist/part kernels)
#define PART_THREADS 512

typedef unsigned int u32;

// ---------------- edge dtype detect ----------------
// int64 edge_index: odd 32-bit words of first 8192 words are all zero (idx < N < 2^31).
__global__ __launch_bounds__(256) void k_detect(const u32* __restrict__ ei, u32* __restrict__ flags) {
    __shared__ int nz;
    if (threadIdx.x == 0) nz = 0;
    __syncthreads();
    for (int i = threadIdx.x; 2 * i + 1 < 8192; i += blockDim.x) {
        if (ei[2 * i + 1] != 0u) atomicAdd(&nz, 1);
    }
    __syncthreads();
    if (threadIdx.x == 0) flags[0] = (nz == 0) ? 2u : 1u;
}

// ---------------- pass A: per-group bucket histogram ----------------
__global__ __launch_bounds__(PART_THREADS) void k_hist(const u32* __restrict__ ei, int E, int B,
                                                       const u32* __restrict__ flags,
                                                       u32* __restrict__ cntGB) {
    __shared__ u32 hist[BMAX];
    for (int t = threadIdx.x; t < B; t += PART_THREADS) hist[t] = 0u;
    __syncthreads();
    u32 strd = flags[0];
    int chunk = (E + GPART - 1) / GPART;
    int e0 = blockIdx.x * chunk;
    int e1 = min(E, e0 + chunk);
    for (int e = e0 + threadIdx.x; e < e1; e += PART_THREADS) {
        u32 d = ei[((size_t)E + (size_t)e) * strd];
        atomicAdd(&hist[d >> 5], 1u);
    }
    __syncthreads();
    for (int t = threadIdx.x; t < B; t += PART_THREADS)
        cntGB[(size_t)blockIdx.x * B + t] = hist[t];
}

// ---------------- pass B1: per-bucket exclusive scan over groups ----------------
__global__ __launch_bounds__(GPART) void k_scanG(const u32* __restrict__ cntGB, int B,
                                                 u32* __restrict__ gbOff, u32* __restrict__ total) {
    __shared__ u32 s[GPART];
    int b = blockIdx.x;
    u32 v = cntGB[(size_t)threadIdx.x * B + b];
    s[threadIdx.x] = v;
    __syncthreads();
    for (int o = 1; o < GPART; o <<= 1) {
        u32 t = (threadIdx.x >= (u32)o) ? s[threadIdx.x - o] : 0u;
        __syncthreads();
        s[threadIdx.x] += t;
        __syncthreads();
    }
    gbOff[(size_t)threadIdx.x * B + b] = s[threadIdx.x] - v;
    if (threadIdx.x == GPART - 1) total[b] = s[GPART - 1];
}

// ---------------- pass B2: exclusive scan of bucket totals ----------------
__global__ __launch_bounds__(256) void k_scanB(const u32* __restrict__ total, int B,
                                               u32* __restrict__ bstart) {
    __shared__ u32 s[256];
    int per = (B + 255) / 256;
    int i0 = threadIdx.x * per;
    int iend = min(B, i0 + per);
    u32 sum = 0u;
    for (int i = i0; i < iend; ++i) sum += total[i];
    s[threadIdx.x] = sum;
    __syncthreads();
    for (int o = 1; o < 256; o <<= 1) {
        u32 t = (threadIdx.x >= (u32)o) ? s[threadIdx.x - o] : 0u;
        __syncthreads();
        s[threadIdx.x] += t;
        __syncthreads();
    }
    u32 run = s[threadIdx.x] - sum;  // exclusive prefix
    for (int i = i0; i < iend; ++i) { bstart[i] = run; run += total[i]; }
    if (threadIdx.x == 255) bstart[B] = s[255];
}

// ---------------- pass C: partition edges into bucket-ordered buffer ----------------
// entry = (src << 5) | (dst & 31); per-(group,bucket) runs are private & contiguous.
__global__ __launch_bounds__(PART_THREADS) void k_part(const u32* __restrict__ ei, int E, int B,
                                                       const u32* __restrict__ flags,
                                                       const u32* __restrict__ gbOff,
                                                       const u32* __restrict__ bstart,
                                                       u32* __restrict__ bbuf) {
    __shared__ u32 cur[BMAX];
    for (int t = threadIdx.x; t < B; t += PART_THREADS)
        cur[t] = bstart[t] + gbOff[(size_t)blockIdx.x * B + t];
    __syncthreads();
    u32 strd = flags[0];
    int chunk = (E + GPART - 1) / GPART;
    int e0 = blockIdx.x * chunk;
    int e1 = min(E, e0 + chunk);
    for (int e = e0 + threadIdx.x; e < e1; e += PART_THREADS) {
        u32 sidx = ei[(size_t)e * strd];
        u32 d = ei[((size_t)E + (size_t)e) * strd];
        u32 p = atomicAdd(&cur[d >> 5], 1u);
        bbuf[p] = (sidx << 5) | (d & 31u);
    }
}

// ---------------- pass D: per-bucket CSR finalize (one block per bucket) ----------------
// Counts 32 nodes in LDS, writes off/cnt/dinv, then fills its private perm window.
__global__ __launch_bounds__(256) void k_csr(const u32* __restrict__ bbuf,
                                             const u32* __restrict__ bstart, int N,
                                             u32* __restrict__ cnt, u32* __restrict__ off,
                                             float* __restrict__ dinv, u32* __restrict__ perm) {
    __shared__ u32 ncnt[32];
    __shared__ u32 ncur[32];
    int b = blockIdx.x;
    u32 base = bstart[b], end = bstart[b + 1];
    if (threadIdx.x < 32) ncnt[threadIdx.x] = 0u;
    __syncthreads();
    for (u32 i = base + threadIdx.x; i < end; i += 256)
        atomicAdd(&ncnt[bbuf[i] & 31u], 1u);
    __syncthreads();
    if (threadIdx.x == 0) {
        u32 run = base;
        for (int i = 0; i < 32; ++i) { ncur[i] = run; run += ncnt[i]; }
    }
    __syncthreads();
    if (threadIdx.x < 32) {
        int node = b * 32 + (int)threadIdx.x;
        if (node < N) {
            u32 c = ncnt[threadIdx.x];
            cnt[node] = c;
            off[node] = ncur[threadIdx.x];
            dinv[node] = rsqrtf((float)(c + 1u));  // +1 self-loop
        }
    }
    __syncthreads();
    for (u32 i = base + threadIdx.x; i < end; i += 256) {
        u32 ent = bbuf[i];
        u32 p = atomicAdd(&ncur[ent & 31u], 1u);
        perm[p] = ent >> 5;
    }
}

// ---------------- h1s[r,:] = (x[r,:] @ W1) * dinv[r] ----------------
__global__ __launch_bounds__(256) void k_xw1(const float* __restrict__ x, const float* __restrict__ W1,
                                             const float* __restrict__ dinv, float* __restrict__ h1s, int n) {
    __shared__ float Ws[F_IN * H1c];  // 8 KB
    for (int t = threadIdx.x; t < F_IN * H1c; t += 256) Ws[t] = W1[t];
    __syncthreads();
    int r = blockIdx.x * 16 + (threadIdx.x >> 4);
    int c = threadIdx.x & 15;
    if (r >= n) return;
    const float* xr = x + (size_t)r * F_IN;
    float a0 = 0.f, a1 = 0.f;
    #pragma unroll
    for (int k = 0; k < F_IN; k += 4) {
        float4 xv = *reinterpret_cast<const float4*>(xr + k);
        a0 += xv.x * Ws[(k + 0) * H1c + c];
        a1 += xv.y * Ws[(k + 1) * H1c + c];
        a0 += xv.z * Ws[(k + 2) * H1c + c];
        a1 += xv.w * Ws[(k + 3) * H1c + c];
    }
    h1s[(size_t)r * H1c + c] = (a0 + a1) * dinv[r];
}

// ---------------- GCN1 aggregate + bias/ReLU + @W2, pre-scale by dinv ----------------
__global__ __launch_bounds__(256) void k_agg1_w2(const float* __restrict__ h1s, const u32* __restrict__ perm,
                                                 const u32* __restrict__ off, const u32* __restrict__ cnt,
                                                 const float* __restrict__ dinv, const float* __restrict__ b1,
                                                 const float* __restrict__ W2, float* __restrict__ h2s, int n) {
    __shared__ float W2s[H1c * H2c];
    __shared__ float h1L[16][H1c + 1];
    for (int t = threadIdx.x; t < H1c * H2c; t += 256) W2s[t] = W2[t];

    int g = threadIdx.x >> 4, j = threadIdx.x & 15;
    int r = blockIdx.x * 16 + g;
    float hv = 0.f;
    if (r < n) {
        u32 s0 = off[r], len = cnt[r];
        float a0 = 0.f, a1 = 0.f, a2 = 0.f, a3 = 0.f;
        u32 it = 0;
        for (; it + 4 <= len; it += 4) {
            u32 e0 = perm[s0 + it], e1 = perm[s0 + it + 1];
            u32 e2 = perm[s0 + it + 2], e3 = perm[s0 + it + 3];
            a0 += h1s[(size_t)e0 * H1c + j];
            a1 += h1s[(size_t)e1 * H1c + j];
            a2 += h1s[(size_t)e2 * H1c + j];
            a3 += h1s[(size_t)e3 * H1c + j];
        }
        for (; it < len; ++it) a0 += h1s[(size_t)perm[s0 + it] * H1c + j];
        float acc = (a0 + a1) + (a2 + a3);
        float dv = dinv[r];
        hv = fmaxf(dv * (acc + h1s[(size_t)r * H1c + j]) + b1[j], 0.f);
    }
    h1L[g][j] = hv;
    __syncthreads();

    int c = threadIdx.x & 31, g2 = threadIdx.x >> 5;
    #pragma unroll
    for (int p = 0; p < 2; ++p) {
        int rr = g2 + p * 8;
        int n2 = blockIdx.x * 16 + rr;
        if (n2 < n) {
            float acc2 = 0.f;
            #pragma unroll
            for (int jj = 0; jj < H1c; ++jj) acc2 += h1L[rr][jj] * W2s[jj * H2c + c];
            h2s[(size_t)n2 * H2c + c] = acc2 * dinv[n2];
        }
    }
}

// ---------------- GCN2 aggregate + bias/ReLU ----------------
__global__ __launch_bounds__(256) void k_agg2(const float* __restrict__ h2s, const u32* __restrict__ perm,
                                              const u32* __restrict__ off, const u32* __restrict__ cnt,
                                              const float* __restrict__ dinv, const float* __restrict__ b2,
                                              float* __restrict__ h2post, int n) {
    int g = threadIdx.x >> 5, j = threadIdx.x & 31;
    int r = blockIdx.x * 8 + g;
    if (r >= n) return;
    u32 s0 = off[r], len = cnt[r];
    float a0 = 0.f, a1 = 0.f, a2 = 0.f, a3 = 0.f;
    u32 it = 0;
    for (; it + 4 <= len; it += 4) {
        u32 e0 = perm[s0 + it], e1 = perm[s0 + it + 1];
        u32 e2 = perm[s0 + it + 2], e3 = perm[s0 + it + 3];
        a0 += h2s[(size_t)e0 * H2c + j];
        a1 += h2s[(size_t)e1 * H2c + j];
        a2 += h2s[(size_t)e2 * H2c + j];
        a3 += h2s[(size_t)e3 * H2c + j];
    }
    for (; it < len; ++it) a0 += h2s[(size_t)perm[s0 + it] * H2c + j];
    float acc = (a0 + a1) + (a2 + a3);
    float dv = dinv[r];
    h2post[(size_t)r * H2c + j] = fmaxf(dv * (acc + h2s[(size_t)r * H2c + j]) + b2[j], 0.f);
}

// ---------------- fused MLP ----------------
__global__ __launch_bounds__(256) void k_mlp(const float* __restrict__ h2post,
                                             const float* __restrict__ Wf1, const float* __restrict__ bf1,
                                             const float* __restrict__ Wf2, const float* __restrict__ bf2,
                                             const float* __restrict__ Wf3, const float* __restrict__ bf3,
                                             float* __restrict__ out, int n) {
    __shared__ float W1s[H2c * H3c];
    __shared__ float W2s[H3c * H4c];
    __shared__ float W3s[H4c * NCc];
    __shared__ float b1s[H3c], b2s[H4c], b3s[NCc];
    for (int t = threadIdx.x; t < H2c * H3c; t += 256) W1s[t] = Wf1[t];
    for (int t = threadIdx.x; t < H3c * H4c; t += 256) W2s[t] = Wf2[t];
    for (int t = threadIdx.x; t < H4c * NCc; t += 256) W3s[t] = Wf3[t];
    if (threadIdx.x < H3c) b1s[threadIdx.x] = bf1[threadIdx.x];
    if (threadIdx.x < H4c) b2s[threadIdx.x] = bf2[threadIdx.x];
    if (threadIdx.x < NCc) b3s[threadIdx.x] = bf3[threadIdx.x];
    __syncthreads();

    int r = blockIdx.x * 256 + threadIdx.x;
    if (r >= n) return;

    float h2v[H2c];
    #pragma unroll
    for (int k = 0; k < H2c; k += 4) {
        float4 v = *reinterpret_cast<const float4*>(h2post + (size_t)r * H2c + k);
        h2v[k] = v.x; h2v[k + 1] = v.y; h2v[k + 2] = v.z; h2v[k + 3] = v.w;
    }
    float a4[H4c];
    #pragma unroll
    for (int k2 = 0; k2 < H4c; ++k2) a4[k2] = b2s[k2];
    #pragma unroll 4
    for (int j = 0; j < H3c; ++j) {
        float t = b1s[j];
        #pragma unroll
        for (int k = 0; k < H2c; ++k) t += h2v[k] * W1s[k * H3c + j];
        t = fmaxf(t, 0.f);
        #pragma unroll
        for (int k2 = 0; k2 < H4c; ++k2) a4[k2] += t * W2s[j * H4c + k2];
    }
    #pragma unroll
    for (int k2 = 0; k2 < H4c; ++k2) a4[k2] = fmaxf(a4[k2], 0.f);

    #pragma unroll
    for (int c0 = 0; c0 < NCc; c0 += 4) {
        float o0 = b3s[c0], o1 = b3s[c0 + 1], o2 = b3s[c0 + 2], o3 = b3s[c0 + 3];
        #pragma unroll
        for (int k2 = 0; k2 < H4c; ++k2) {
            float a = a4[k2];
            o0 += a * W3s[k2 * NCc + c0];
            o1 += a * W3s[k2 * NCc + c0 + 1];
            o2 += a * W3s[k2 * NCc + c0 + 2];
            o3 += a * W3s[k2 * NCc + c0 + 3];
        }
        *reinterpret_cast<float4*>(out + (size_t)r * NCc + c0) = make_float4(o0, o1, o2, o3);
    }
}

extern "C" void kernel_launch(void* const* d_in, const int* in_sizes, int n_in,
                              void* d_out, int out_size, void* d_ws, size_t ws_size,
                              hipStream_t stream) {
    const float* x   = (const float*)d_in[0];
    const float* W1  = (const float*)d_in[1];
    const float* b1  = (const float*)d_in[2];
    const float* W2  = (const float*)d_in[3];
    const float* b2  = (const float*)d_in[4];
    const float* Wf1 = (const float*)d_in[5];
    const float* bf1 = (const float*)d_in[6];
    const float* Wf2 = (const float*)d_in[7];
    const float* bf2 = (const float*)d_in[8];
    const float* Wf3 = (const float*)d_in[9];
    const float* bf3 = (const float*)d_in[10];
    const u32*   ei  = (const u32*)d_in[11];

    int N = in_sizes[0] / F_IN;
    int E = in_sizes[11] / 2;
    int B = (N + 31) >> 5;          // 32-node buckets
    if (B > BMAX) return;           // fixed-size problem guard

    // workspace layout
    char* w = (char*)d_ws;
    u32* cnt    = (u32*)w;   w += (size_t)N * 4;
    u32* off    = (u32*)w;   w += (size_t)N * 4;
    u32* flags  = (u32*)w;   w += 16 * 4;
    float* dinv = (float*)w; w += (size_t)N * 4;
    float* h2p  = (float*)w; w += (size_t)N * H2c * 4;
    u32* perm   = (u32*)w;   w += (size_t)E * 4;
    u32* bbuf   = (u32*)w;   w += (size_t)E * 4;     // dead after k_csr
    u32* cntGB  = (u32*)w;   w += (size_t)GPART * BMAX * 4;
    u32* gbOff  = (u32*)w;   w += (size_t)GPART * BMAX * 4;
    u32* total  = (u32*)w;   w += (size_t)(BMAX + 8) * 4;
    u32* bstart = (u32*)w;   w += (size_t)(BMAX + 8) * 4;
    // h1s/h2s alias bbuf's storage (bbuf is dead once k_csr finishes)
    float* h1s  = (float*)bbuf;                        // N*16 floats (6.4 MB < 25.6 MB)
    float* h2s  = (float*)(bbuf + (size_t)N * H1c);    // N*32 floats

    k_detect<<<1, 256, 0, stream>>>(ei, flags);
    k_hist  <<<GPART, PART_THREADS, 0, stream>>>(ei, E, B, flags, cntGB);
    k_scanG <<<B, GPART, 0, stream>>>(cntGB, B, gbOff, total);
    k_scanB <<<1, 256, 0, stream>>>(total, B, bstart);
    k_part  <<<GPART, PART_THREADS, 0, stream>>>(ei, E, B, flags, gbOff, bstart, bbuf);
    k_csr   <<<B, 256, 0, stream>>>(bbuf, bstart, N, cnt, off, dinv, perm);

    int nb16 = (N + 15) / 16;
    k_xw1<<<nb16, 256, 0, stream>>>(x, W1, dinv, h1s, N);
    k_agg1_w2<<<nb16, 256, 0, stream>>>(h1s, perm, off, cnt, dinv, b1, W2, h2s, N);
    int nb8 = (N + 7) / 8;
    k_agg2<<<nb8, 256, 0, stream>>>(h2s, perm, off, cnt, dinv, b2, h2p, N);
    int nbN = (N + 255) / 256;
    k_mlp<<<nbN, 256, 0, stream>>>(h2p, Wf1, bf1, Wf2, bf2, Wf3, bf3, (float*)d_out, N);
}